// Round 7
// baseline (18.277 us; speedup 1.0000x reference)
//
#include <hip/hip_runtime.h>
#include <stdint.h>

// ---------------------------------------------------------------------------
// JAX Threefry-2x32, x32 + threefry_partitionable=True.
// HW-verified (absmax fingerprints r0-r6):
//   - foldlike split rows, partitionable 32-bit fold at counter (0, flat),
//     row-major layout, u01 formula, f32 prob arithmetic: bit-exact
//     (inclusion+mask flags match the reference everywhere).
//   - legacy scheme, x64 scheme: excluded (32764 total-mismatch signature).
//   - randint from ONE (2,)+shape draw over k_ids (both unpack orders) and
//     64-bit packed draw: excluded (near-miss signatures).
// ==> deployed _randint derives higher/lower from SPLIT SUBKEYS of k_ids:
//       k1, k2 = split(k_ids); higher = bits(k1,32,shape); lower = bits(k2,...)
//     (foldlike: k1 = tf(k_ids,(0,0)), k2 = tf(k_ids,(0,1)); counters (0,j)).
// ---------------------------------------------------------------------------

struct TFR { uint32_t x0, x1; };

__host__ __device__ constexpr TFR tf2x32(uint32_t k0, uint32_t k1,
                                         uint32_t c0, uint32_t c1) {
  uint32_t ks2 = k0 ^ k1 ^ 0x1BD11BDAu;
  uint32_t x0 = c0 + k0;
  uint32_t x1 = c1 + k1;
#define TF_ROUND(r) { x0 += x1; x1 = (x1 << (r)) | (x1 >> (32 - (r))); x1 ^= x0; }
  TF_ROUND(13) TF_ROUND(15) TF_ROUND(26) TF_ROUND(6)
  x0 += k1;  x1 += ks2 + 1u;
  TF_ROUND(17) TF_ROUND(29) TF_ROUND(16) TF_ROUND(24)
  x0 += ks2; x1 += k0 + 2u;
  TF_ROUND(13) TF_ROUND(15) TF_ROUND(26) TF_ROUND(6)
  x0 += k0;  x1 += k1 + 3u;
  TF_ROUND(17) TF_ROUND(29) TF_ROUND(16) TF_ROUND(24)
  x0 += k1;  x1 += ks2 + 4u;
  TF_ROUND(13) TF_ROUND(15) TF_ROUND(26) TF_ROUND(6)
  x0 += ks2; x1 += k0 + 5u;
#undef TF_ROUND
  return TFR{x0, x1};
}

// Random123 reference vectors — build fails if the core is ever wrong.
static_assert(tf2x32(0u, 0u, 0u, 0u).x0 == 0x6b200159u, "tf vec0 x0");
static_assert(tf2x32(0u, 0u, 0u, 0u).x1 == 0x99ba4efeu, "tf vec0 x1");
static_assert(tf2x32(0xffffffffu, 0xffffffffu, 0xffffffffu, 0xffffffffu).x0 == 0x1cb996fcu, "tf vec1 x0");
static_assert(tf2x32(0xffffffffu, 0xffffffffu, 0xffffffffu, 0xffffffffu).x1 == 0xbb002be7u, "tf vec1 x1");
static_assert(tf2x32(0x13198a2eu, 0x03707344u, 0x243f6a88u, 0x85a308d3u).x0 == 0xc4923a9cu, "tf vec2 x0");
static_assert(tf2x32(0x13198a2eu, 0x03707344u, 0x243f6a88u, 0x85a308d3u).x1 == 0x483df7a0u, "tf vec2 x1");

// split(key(42), 4), foldlike: key_i = tf((0,42), (0,i)).
// Rows 0,1 hardware-verified by the flag-match fingerprint.
constexpr TFR K_INC  = tf2x32(0u, 42u, 0u, 0u);
constexpr TFR K_MASK = tf2x32(0u, 42u, 0u, 1u);
constexpr TFR K_RAND = tf2x32(0u, 42u, 0u, 2u);
constexpr TFR K_IDS  = tf2x32(0u, 42u, 0u, 3u);

// ROUND-6 (V_e): randint subkeys = split(k_ids, 2) rows, constant-folded.
constexpr TFR K_IDS_HI = tf2x32(K_IDS.x0, K_IDS.x1, 0u, 0u);  // k1 -> higher
constexpr TFR K_IDS_LO = tf2x32(K_IDS.x0, K_IDS.x1, 0u, 1u);  // k2 -> lower

// partitionable random_bits(32): element e -> tf(key, (0, e)).x0 ^ .x1
__device__ __forceinline__ uint32_t bits32(uint32_t k0, uint32_t k1, uint32_t e) {
  TFR r = tf2x32(k0, k1, 0u, e);
  return r.x0 ^ r.x1;
}

__device__ __forceinline__ float u01f(uint32_t b) {
  return __uint_as_float((b >> 9) | 0x3f800000u) - 1.0f;
}

__global__ __launch_bounds__(256) void mlm_mask_kernel(
    const int* __restrict__ input_ids,
    const int* __restrict__ labels,
    const float* __restrict__ mask_prob,
    const float* __restrict__ keep_replace_prob,
    const int* __restrict__ special_tokens, int n_special,
    const int* __restrict__ standard_tokens, int n_standard,
    int mask_token,
    const int* __restrict__ mask_token_id_p,
    int* __restrict__ out_ids,
    int* __restrict__ out_labels,
    int n)
{
  int j = blockIdx.x * blockDim.x + threadIdx.x;
  if (j >= n) return;

  float mp  = mask_prob[0];
  float krp = keep_replace_prob[0];
  float mlm_prob     = mp + 2.0f * krp;   // exact-f32 order matches JAX
  float mask_portion = mp / mlm_prob;

  int mtok = mask_token_id_p ? mask_token_id_p[0] : mask_token;

  int id  = input_ids[j];
  int lab = labels[j];

  bool special = false;
  for (int t = 0; t < n_special; ++t) special = special || (id == special_tokens[t]);

  uint32_t uj = (uint32_t)j;

  bool inclusion = (!special) &&
                   (u01f(bits32(K_INC.x0, K_INC.x1, uj)) < mlm_prob);

  int out_lab = inclusion ? lab : -100;
  int out_id  = id;

  if (inclusion) {
    if (u01f(bits32(K_MASK.x0, K_MASK.x1, uj)) < mask_portion) {
      out_id = mtok;
    } else {
      if (u01f(bits32(K_RAND.x0, K_RAND.x1, uj)) < 0.5f) {
        // ROUND-6 CHANGE (V_e): higher/lower from split subkeys of k_ids,
        // each a plain 32-bit partitionable draw at counter (0, j).
        uint32_t hi = bits32(K_IDS_HI.x0, K_IDS_HI.x1, uj);
        uint32_t lo = bits32(K_IDS_LO.x0, K_IDS_LO.x1, uj);
        uint32_t span = (uint32_t)n_standard;          // 32763
        uint32_t m = 65536u % span;                    // 10
        m = (uint32_t)(((uint64_t)m * (uint64_t)m) % (uint64_t)span);  // 100
        // wrap-free in uint32, matches JAX unsigned arithmetic exactly
        uint32_t off = (uint32_t)((((uint64_t)(hi % span)) * (uint64_t)m
                                   + (uint64_t)(lo % span)) % (uint64_t)span);
        out_id = standard_tokens[off];
      }
    }
  }

  out_ids[j]    = out_id;
  out_labels[j] = out_lab;
}

extern "C" void kernel_launch(void* const* d_in, const int* in_sizes, int n_in,
                              void* d_out, int out_size, void* d_ws, size_t ws_size,
                              hipStream_t stream) {
  const int*   input_ids         = (const int*)  d_in[0];
  const int*   labels            = (const int*)  d_in[1];
  const float* mask_prob         = (const float*)d_in[2];
  const float* keep_replace_prob = (const float*)d_in[3];
  const int*   special_tokens    = (const int*)  d_in[4];
  const int*   standard_tokens   = (const int*)  d_in[5];
  const int*   mask_token_id     = (n_in > 6) ? (const int*)d_in[6] : nullptr;

  int n          = in_sizes[0];      // B*S = 1048576
  int n_special  = in_sizes[4];      // 5
  int n_standard = in_sizes[5];      // 32763

  int* out_ids    = (int*)d_out;
  int* out_labels = ((int*)d_out) + n;

  int block = 256;
  int grid  = (n + block - 1) / block;
  mlm_mask_kernel<<<grid, block, 0, stream>>>(
      input_ids, labels, mask_prob, keep_replace_prob,
      special_tokens, n_special, standard_tokens, n_standard,
      /*mask_token=*/4, mask_token_id, out_ids, out_labels, n);
}